// Round 2
// baseline (188.986 us; speedup 1.0000x reference)
//
#include <hip/hip_runtime.h>
#include <hip/hip_bf16.h>
#include <math.h>

#define NROWS 8192
#define DIM 64
#define NTILE 64          // 8192 / 128 tiles per side
#define NPAIRS 2080       // NTILE*(NTILE+1)/2 upper-triangular tile pairs
#define NGRAM  (2 * NPAIRS)

typedef __bf16 bf16x8 __attribute__((ext_vector_type(8)));
typedef float f32x4 __attribute__((ext_vector_type(4)));

// ws layout (all partials written fresh every launch; no atomics except the
// last-block counter):
//   @0      : part_align float[2048]       (one per gather block)
//   @8192   : part_gram  float[2*NPAIRS]   (one per gram block, z-major; ends @24832)
//   @28672  : done_counter uint            (zeroed by gather_norm each launch)
//   @32768  : Xu bf16[8192*64]  (1 MB)
//   @32768+1MB : Xp bf16[8192*64]  (1 MB)

__global__ __launch_bounds__(256) void gather_norm_kernel(
    const int* __restrict__ user_id, const int* __restrict__ pos_id,
    const float* __restrict__ user_table, const float* __restrict__ item_table,
    float* __restrict__ part_align,
    __hip_bfloat16* __restrict__ Xu, __hip_bfloat16* __restrict__ Xp,
    unsigned* __restrict__ done_counter)
{
    if (blockIdx.x == 0 && threadIdx.x == 0) *done_counter = 0u;

    const int lane = threadIdx.x & 63;
    const int w    = threadIdx.x >> 6;          // wave in block, 0..3
    const int row  = blockIdx.x * 4 + w;        // one wave per batch row

    const float u = user_table[(long)user_id[row] * DIM + lane];
    const float p = item_table[(long)pos_id[row] * DIM + lane];

    float su = u * u, sp = p * p;
    #pragma unroll
    for (int m = 32; m >= 1; m >>= 1) {
        su += __shfl_xor(su, m, 64);
        sp += __shfl_xor(sp, m, 64);
    }
    const float un = u * rsqrtf(su);
    const float pn = p * rsqrtf(sp);

    Xu[row * DIM + lane] = __float2bfloat16(un);
    Xp[row * DIM + lane] = __float2bfloat16(pn);

    const float d = un - pn;
    float dd = d * d;
    #pragma unroll
    for (int m = 32; m >= 1; m >>= 1) dd += __shfl_xor(dd, m, 64);

    __shared__ float red[4];
    if (lane == 0) red[w] = dd;
    __syncthreads();
    if (threadIdx.x == 0)
        part_align[blockIdx.x] = red[0] + red[1] + red[2] + red[3];  // no atomic
}

// One block per upper-triangular 128x128 tile pair (bi <= bj), decoded from a
// 1D triangular index — no dead blocks. Each block: stage both 128-row x 64-col
// bf16 panels (16 KB each) into LDS cooperatively (coalesced 16B global loads,
// XOR-16B swizzled ds_write_b128 so the 128B row stride doesn't alias banks),
// then 4 waves in 2x2, each wave a 64x64 sub-tile as 4x4 grid of 16x16x32 bf16
// MFMAs (K=64 = 2 k-steps), fragments via conflict-free swizzled ds_read_b128.
// Epilogue exp2 is interleaved per mt-row so only 4 f32x4 accumulators are
// live at once (VGPR -> occupancy). The LAST block (device-scope counter)
// performs the finalize inline — no third kernel launch.
__global__ __launch_bounds__(256) void gram_exp_kernel(
    const __hip_bfloat16* __restrict__ Xu, const __hip_bfloat16* __restrict__ Xp,
    float* __restrict__ part_gram, const float* __restrict__ part_align,
    unsigned* __restrict__ done_counter, float* __restrict__ out)
{
    const int t = blockIdx.x;           // 0..NPAIRS-1
    const int z = blockIdx.y;           // 0 = user, 1 = pos
    const __hip_bfloat16* __restrict__ X = (z == 0) ? Xu : Xp;

    // decode lower-tri pair (i >= j): t = i*(i+1)/2 + j
    int i = (int)((sqrtf(8.0f * (float)t + 1.0f) - 1.0f) * 0.5f);
    while (i * (i + 1) / 2 > t) --i;
    while ((i + 1) * (i + 2) / 2 <= t) ++i;
    const int j = t - i * (i + 1) / 2;
    const int bi = j, bj = i;           // bi <= bj

    const int tid  = threadIdx.x;
    const int lane = tid & 63;
    const int w    = tid >> 6;          // 0..3
    const int wr   = w >> 1, wc = w & 1;
    const int r    = lane & 15;         // row within 16-tile
    const int quad = lane >> 4;         // 0..3: which 16B k-slot

    // Two panels, 16 KB each. Swizzle s(x) = x ^ (((x>>7)&7)<<4):
    // involution, permutes the eight 16B slots within each 128B row by the
    // row's low 3 bits -> every consecutive-8-lane group of a ds_read_b128 /
    // ds_write_b128 covers all 32 banks (conflict-free).
    __shared__ __align__(16) char lds[2 * 16384];

    {
        const char* srcA = (const char*)(X + (size_t)bi * 128 * DIM);
        const char* srcB = (const char*)(X + (size_t)bj * 128 * DIM);
        const int l16 = lane * 16;
        #pragma unroll
        for (int k = 0; k < 4; ++k) {
            const int x  = w * 4096 + k * 1024 + l16;   // linear panel byte
            const int sx = x ^ (((x >> 7) & 7) << 4);   // swizzled LDS slot
            *reinterpret_cast<bf16x8*>(lds + sx) =
                *reinterpret_cast<const bf16x8*>(srcA + x);
            *reinterpret_cast<bf16x8*>(lds + 16384 + sx) =
                *reinterpret_cast<const bf16x8*>(srcB + x);
        }
    }
    __syncthreads();

    bf16x8 a[4][2], b[4][2];
    #pragma unroll
    for (int tt = 0; tt < 4; ++tt) {
        const int rowA = wr * 64 + tt * 16 + r;
        const int cA   = (quad * 16) ^ ((rowA & 7) << 4);
        a[tt][0] = *reinterpret_cast<const bf16x8*>(lds + rowA * 128 + cA);
        a[tt][1] = *reinterpret_cast<const bf16x8*>(lds + rowA * 128 + (cA ^ 64));
        const int rowB = wc * 64 + tt * 16 + r;
        const int cB   = (quad * 16) ^ ((rowB & 7) << 4);
        b[tt][0] = *reinterpret_cast<const bf16x8*>(lds + 16384 + rowB * 128 + cB);
        b[tt][1] = *reinterpret_cast<const bf16x8*>(lds + 16384 + rowB * 128 + (cB ^ 64));
    }

    // e = exp(4*sim - 4) = exp2(C4*sim - C4); sum all 64 values per thread.
    // Epilogue interleaved per mt-row: only c[4] (16 VGPRs) of accumulator
    // live at a time instead of 64. Same per-element op order as before ->
    // bit-identical sum. 4 independent accumulators break the add chain.
    const float C4 = 5.770780163555851f;  // 4 * log2(e)
    float s0 = 0.f, s1 = 0.f, s2 = 0.f, s3 = 0.f;
    #pragma unroll
    for (int mt = 0; mt < 4; ++mt) {
        f32x4 c[4];
        #pragma unroll
        for (int nt = 0; nt < 4; ++nt) {
            f32x4 cc = {0.f, 0.f, 0.f, 0.f};
            cc = __builtin_amdgcn_mfma_f32_16x16x32_bf16(a[mt][0], b[nt][0], cc, 0, 0, 0);
            cc = __builtin_amdgcn_mfma_f32_16x16x32_bf16(a[mt][1], b[nt][1], cc, 0, 0, 0);
            c[nt] = cc;
        }
        #pragma unroll
        for (int nt = 0; nt < 4; ++nt) {
            s0 += __builtin_amdgcn_exp2f(fmaf(C4, c[nt][0], -C4));
            s1 += __builtin_amdgcn_exp2f(fmaf(C4, c[nt][1], -C4));
            s2 += __builtin_amdgcn_exp2f(fmaf(C4, c[nt][2], -C4));
            s3 += __builtin_amdgcn_exp2f(fmaf(C4, c[nt][3], -C4));
        }
    }
    float s = (s0 + s1) + (s2 + s3);

    #pragma unroll
    for (int m = 32; m >= 1; m >>= 1) s += __shfl_xor(s, m, 64);

    __shared__ float red[4];
    __shared__ int sOld;
    if (lane == 0) red[w] = s;
    __syncthreads();
    if (tid == 0) {
        const float wgt = (bi == bj) ? 1.f : 2.f;
        part_gram[z * NPAIRS + t] = wgt * (red[0] + red[1] + red[2] + red[3]);
        __threadfence();                                  // release partial
        sOld = (int)atomicAdd(done_counter, 1u);          // device scope
    }
    __syncthreads();
    if (sOld != NGRAM - 1) return;

    // ---- last block: finalize inline (replaces the 3rd kernel) ----
    __threadfence();                                      // acquire partials

    float a2 = 0.f, su = 0.f, sp = 0.f;
    for (int k = tid; k < 2048; k += 256)   a2 += part_align[k];
    for (int k = tid; k < NPAIRS; k += 256) su += part_gram[k];
    for (int k = tid; k < NPAIRS; k += 256) sp += part_gram[NPAIRS + k];

    #pragma unroll
    for (int m = 32; m >= 1; m >>= 1) {
        a2 += __shfl_xor(a2, m, 64);
        su += __shfl_xor(su, m, 64);
        sp += __shfl_xor(sp, m, 64);
    }
    __shared__ float ra[4], ru[4], rp[4];
    if (lane == 0) { ra[w] = a2; ru[w] = su; rp[w] = sp; }
    __syncthreads();
    if (tid == 0) {
        const float A  = ra[0] + ra[1] + ra[2] + ra[3];
        const float SU = ru[0] + ru[1] + ru[2] + ru[3];
        const float SP = rp[0] + rp[1] + rp[2] + rp[3];
        const float n = 8192.f;
        const float npairs = 8192.f * 8191.f * 0.5f;
        const float pu = (SU - n) * 0.5f;
        const float pp = (SP - n) * 0.5f;
        out[0] = A / n + 0.5f * (logf(pu / npairs) + logf(pp / npairs));  // GAMMA=1
    }
}

extern "C" void kernel_launch(void* const* d_in, const int* in_sizes, int n_in,
                              void* d_out, int out_size, void* d_ws, size_t ws_size,
                              hipStream_t stream)
{
    const int*   user_id    = (const int*)d_in[0];
    const int*   pos_id     = (const int*)d_in[1];
    // d_in[2] = neg_id (unused by the reference output)
    const float* user_table = (const float*)d_in[3];
    const float* item_table = (const float*)d_in[4];
    float* out = (float*)d_out;

    float*    part_align   = (float*)d_ws;                      // 2048 floats
    float*    part_gram    = (float*)((char*)d_ws + 8192);      // 2*NPAIRS floats
    unsigned* done_counter = (unsigned*)((char*)d_ws + 28672);  // 1 uint
    __hip_bfloat16* Xu = (__hip_bfloat16*)((char*)d_ws + 32768);
    __hip_bfloat16* Xp = Xu + (size_t)NROWS * DIM;

    gather_norm_kernel<<<NROWS / 4, 256, 0, stream>>>(
        user_id, pos_id, user_table, item_table, part_align, Xu, Xp, done_counter);

    gram_exp_kernel<<<dim3(NPAIRS, 2), 256, 0, stream>>>(
        Xu, Xp, part_gram, part_align, done_counter, out);
}

// Round 3
// 113.165 us; speedup vs baseline: 1.6700x; 1.6700x over previous
//
#include <hip/hip_runtime.h>
#include <hip/hip_bf16.h>
#include <math.h>

#define NROWS 8192
#define DIM 64
#define NTILE 32          // 8192 / 256 tiles per side
#define NPAIRS 528        // NTILE*(NTILE+1)/2 upper-triangular tile pairs

typedef __bf16 bf16x8 __attribute__((ext_vector_type(8)));
typedef float f32x4 __attribute__((ext_vector_type(4)));

// ws layout (all partials written fresh every launch; no atomics, no fences):
//   @0      : part_align float[2048]       (one per gather block)
//   @8192   : part_gram  float[2*NPAIRS]   (one per gram block, z-major)
//   @32768  : Xu bf16[8192*64]  (1 MB)
//   @32768+1MB : Xp bf16[8192*64]  (1 MB)

__global__ __launch_bounds__(256) void gather_norm_kernel(
    const int* __restrict__ user_id, const int* __restrict__ pos_id,
    const float* __restrict__ user_table, const float* __restrict__ item_table,
    float* __restrict__ part_align,
    __hip_bfloat16* __restrict__ Xu, __hip_bfloat16* __restrict__ Xp)
{
    const int lane = threadIdx.x & 63;
    const int w    = threadIdx.x >> 6;          // wave in block, 0..3
    const int row  = blockIdx.x * 4 + w;        // one wave per batch row

    const float u = user_table[(long)user_id[row] * DIM + lane];
    const float p = item_table[(long)pos_id[row] * DIM + lane];

    float su = u * u, sp = p * p;
    #pragma unroll
    for (int m = 32; m >= 1; m >>= 1) {
        su += __shfl_xor(su, m, 64);
        sp += __shfl_xor(sp, m, 64);
    }
    const float un = u * rsqrtf(su);
    const float pn = p * rsqrtf(sp);

    Xu[row * DIM + lane] = __float2bfloat16(un);
    Xp[row * DIM + lane] = __float2bfloat16(pn);

    const float d = un - pn;
    float dd = d * d;
    #pragma unroll
    for (int m = 32; m >= 1; m >>= 1) dd += __shfl_xor(dd, m, 64);

    __shared__ float red[4];
    if (lane == 0) red[w] = dd;
    __syncthreads();
    if (threadIdx.x == 0)
        part_align[blockIdx.x] = red[0] + red[1] + red[2] + red[3];  // no atomic
}

// One block per upper-triangular 256x256 tile pair (bi <= bj), decoded from a
// 1D triangular index — no dead blocks. Each block: stage both 256-row x 64-col
// bf16 panels (32 KB each) into LDS cooperatively (coalesced 16B global loads,
// XOR-16B swizzled writes so the 128B row stride doesn't alias banks), then
// 4 waves in 2x2, each wave a 128x128 sub-tile. B-fragments (8x2 bf16x8 =
// 128 VGPRs) stay register-resident; per mt-row the 2 A-fragments are re-read
// from LDS and the 8 f32x4 accumulators are consumed by the exp2 epilogue
// immediately (peak live ~190 VGPR, no spill). vs 128^2 tiles this halves L2
// panel traffic (136->67 MB) and quarters block count. No atomics/fences.
__global__ __launch_bounds__(256) void gram_exp_kernel(
    const __hip_bfloat16* __restrict__ Xu, const __hip_bfloat16* __restrict__ Xp,
    float* __restrict__ part_gram)
{
    const int t = blockIdx.x;           // 0..NPAIRS-1
    const int z = blockIdx.y;           // 0 = user, 1 = pos
    const __hip_bfloat16* __restrict__ X = (z == 0) ? Xu : Xp;

    // decode lower-tri pair (i >= j): t = i*(i+1)/2 + j
    int i = (int)((sqrtf(8.0f * (float)t + 1.0f) - 1.0f) * 0.5f);
    while (i * (i + 1) / 2 > t) --i;
    while ((i + 1) * (i + 2) / 2 <= t) ++i;
    const int j = t - i * (i + 1) / 2;
    const int bi = j, bj = i;           // bi <= bj

    const int tid  = threadIdx.x;
    const int lane = tid & 63;
    const int w    = tid >> 6;          // 0..3
    const int wr   = w >> 1, wc = w & 1;
    const int r    = lane & 15;         // row within 16-tile
    const int quad = lane >> 4;         // 0..3: which 16B k-slot

    // Two panels, 32 KB each. Swizzle s(x) = x ^ (((x>>7)&7)<<4):
    // involution, permutes the eight 16B slots within each 128B row by the
    // row's low 3 bits -> every consecutive-8-lane group of a b128 access
    // covers all 32 banks (conflict-free; verified SQ_LDS_BANK_CONFLICT=0).
    __shared__ __align__(16) char lds[2 * 32768];

    {
        const char* srcA = (const char*)(X + (size_t)bi * 256 * DIM);
        const char* srcB = (const char*)(X + (size_t)bj * 256 * DIM);
        #pragma unroll
        for (int k = 0; k < 8; ++k) {
            const int x  = (k * 256 + tid) * 16;        // linear panel byte
            const int sx = x ^ (((x >> 7) & 7) << 4);   // swizzled LDS slot
            *reinterpret_cast<bf16x8*>(lds + sx) =
                *reinterpret_cast<const bf16x8*>(srcA + x);
            *reinterpret_cast<bf16x8*>(lds + 32768 + sx) =
                *reinterpret_cast<const bf16x8*>(srcB + x);
        }
    }
    __syncthreads();

    // B fragments register-resident for the whole block.
    bf16x8 b[8][2];
    #pragma unroll
    for (int tt = 0; tt < 8; ++tt) {
        const int rowB = wc * 128 + tt * 16 + r;
        const int cB   = (quad * 16) ^ ((rowB & 7) << 4);
        b[tt][0] = *reinterpret_cast<const bf16x8*>(lds + 32768 + rowB * 128 + cB);
        b[tt][1] = *reinterpret_cast<const bf16x8*>(lds + 32768 + rowB * 128 + (cB ^ 64));
    }

    // e = exp(4*sim - 4) = exp2(C4*sim - C4); sum all values per thread.
    // Per mt-row: re-read 2 A-fragments from LDS, 16 MFMAs into c[8],
    // consume with exp2 immediately. 4 independent accumulators break the
    // serial add chain. All indices compile-time (full unroll) -> registers.
    const float C4 = 5.770780163555851f;  // 4 * log2(e)
    float s0 = 0.f, s1 = 0.f, s2 = 0.f, s3 = 0.f;
    #pragma unroll
    for (int mt = 0; mt < 8; ++mt) {
        const int rowA = wr * 128 + mt * 16 + r;
        const int cA   = (quad * 16) ^ ((rowA & 7) << 4);
        const bf16x8 a0 = *reinterpret_cast<const bf16x8*>(lds + rowA * 128 + cA);
        const bf16x8 a1 = *reinterpret_cast<const bf16x8*>(lds + rowA * 128 + (cA ^ 64));

        f32x4 c[8];
        #pragma unroll
        for (int nt = 0; nt < 8; ++nt) {
            f32x4 cc = {0.f, 0.f, 0.f, 0.f};
            cc = __builtin_amdgcn_mfma_f32_16x16x32_bf16(a0, b[nt][0], cc, 0, 0, 0);
            cc = __builtin_amdgcn_mfma_f32_16x16x32_bf16(a1, b[nt][1], cc, 0, 0, 0);
            c[nt] = cc;
        }
        #pragma unroll
        for (int nt = 0; nt < 8; ++nt) {
            s0 += __builtin_amdgcn_exp2f(fmaf(C4, c[nt][0], -C4));
            s1 += __builtin_amdgcn_exp2f(fmaf(C4, c[nt][1], -C4));
            s2 += __builtin_amdgcn_exp2f(fmaf(C4, c[nt][2], -C4));
            s3 += __builtin_amdgcn_exp2f(fmaf(C4, c[nt][3], -C4));
        }
    }
    float s = (s0 + s1) + (s2 + s3);

    #pragma unroll
    for (int m = 32; m >= 1; m >>= 1) s += __shfl_xor(s, m, 64);

    __shared__ float red[4];
    if (lane == 0) red[w] = s;
    __syncthreads();
    if (tid == 0) {
        const float wgt = (bi == bj) ? 1.f : 2.f;
        part_gram[z * NPAIRS + t] = wgt * (red[0] + red[1] + red[2] + red[3]);
    }
}

__global__ __launch_bounds__(256) void finalize_kernel(
    const float* __restrict__ part_align, const float* __restrict__ part_gram,
    float* __restrict__ out)
{
    float a = 0.f, su = 0.f, sp = 0.f;
    for (int k = threadIdx.x; k < 2048; k += 256)   a  += part_align[k];
    for (int k = threadIdx.x; k < NPAIRS; k += 256) su += part_gram[k];
    for (int k = threadIdx.x; k < NPAIRS; k += 256) sp += part_gram[NPAIRS + k];

    #pragma unroll
    for (int m = 32; m >= 1; m >>= 1) {
        a  += __shfl_xor(a, m, 64);
        su += __shfl_xor(su, m, 64);
        sp += __shfl_xor(sp, m, 64);
    }
    __shared__ float ra[4], ru[4], rp[4];
    const int w = threadIdx.x >> 6, lane = threadIdx.x & 63;
    if (lane == 0) { ra[w] = a; ru[w] = su; rp[w] = sp; }
    __syncthreads();
    if (threadIdx.x == 0) {
        const float A  = ra[0] + ra[1] + ra[2] + ra[3];
        const float SU = ru[0] + ru[1] + ru[2] + ru[3];
        const float SP = rp[0] + rp[1] + rp[2] + rp[3];
        const float n = 8192.f;
        const float npairs = 8192.f * 8191.f * 0.5f;
        const float pu = (SU - n) * 0.5f;
        const float pp = (SP - n) * 0.5f;
        out[0] = A / n + 0.5f * (logf(pu / npairs) + logf(pp / npairs));  // GAMMA=1
    }
}

extern "C" void kernel_launch(void* const* d_in, const int* in_sizes, int n_in,
                              void* d_out, int out_size, void* d_ws, size_t ws_size,
                              hipStream_t stream)
{
    const int*   user_id    = (const int*)d_in[0];
    const int*   pos_id     = (const int*)d_in[1];
    // d_in[2] = neg_id (unused by the reference output)
    const float* user_table = (const float*)d_in[3];
    const float* item_table = (const float*)d_in[4];
    float* out = (float*)d_out;

    float* part_align = (float*)d_ws;                         // 2048 floats
    float* part_gram  = (float*)((char*)d_ws + 8192);         // 2*NPAIRS floats
    __hip_bfloat16* Xu = (__hip_bfloat16*)((char*)d_ws + 32768);
    __hip_bfloat16* Xp = Xu + (size_t)NROWS * DIM;

    gather_norm_kernel<<<NROWS / 4, 256, 0, stream>>>(
        user_id, pos_id, user_table, item_table, part_align, Xu, Xp);

    gram_exp_kernel<<<dim3(NPAIRS, 2), 256, 0, stream>>>(Xu, Xp, part_gram);

    finalize_kernel<<<1, 256, 0, stream>>>(part_align, part_gram, out);
}